// Round 5
// baseline (905.197 us; speedup 1.0000x reference)
//
#include <hip/hip_runtime.h>
#include <hip/hip_bf16.h>
#include <cstdint>

#define CCH 48
#define DD 128
#define HH 128
#define WW 128
#define NVOX (DD*HH*WW)        // 2,097,152 voxels
#define NPTS 2097152
#define NBINS 4096             // 16x16x16 bins of 8^3 voxels

typedef unsigned int uint;
typedef unsigned short ushort_t;
typedef float f32x4 __attribute__((ext_vector_type(4)));

__device__ __forceinline__ ushort_t f2bf_rne(float f) {
    uint u = __float_as_uint(f);
    uint r = (u + 0x7fffu + ((u >> 16) & 1u)) >> 16;
    return (ushort_t)r;
}

// Shared geometry: point -> clamped base voxel + weights (must match across kernels)
struct PtGeo {
    int x0, y0, z0, x1, y1, z1;
    float wx, wy, wz;
};
__device__ __forceinline__ PtGeo pt_geo(const float* __restrict__ pts, int n) {
    PtGeo g;
    const float ix = (pts[n*3+0] + 1.0f) * 63.5f;
    const float iy = (pts[n*3+1] + 1.0f) * 63.5f;
    const float iz = (pts[n*3+2] + 1.0f) * 63.5f;
    const float xf = floorf(ix), yf = floorf(iy), zf = floorf(iz);
    g.wx = ix - xf; g.wy = iy - yf; g.wz = iz - zf;
    int x0 = (int)xf, y0 = (int)yf, z0 = (int)zf;
    g.x0 = min(max(x0,0), WW-1); g.x1 = min(max(x0+1,0), WW-1);
    g.y0 = min(max(y0,0), HH-1); g.y1 = min(max(y0+1,0), HH-1);
    g.z0 = min(max(z0,0), DD-1); g.z1 = min(max(z0+1,0), DD-1);
    return g;
}
__device__ __forceinline__ int pt_bin(const PtGeo& g) {
    return ((g.z0 >> 3) << 8) | ((g.y0 >> 3) << 4) | (g.x0 >> 3);
}

// ---------------------------------------------------------------------------
// Kernel 1 v3: wave-structured transpose. 8 voxels per wave, 48 active lanes.
// Lane (c = lane/8, v = lane%8) computes chunk c (channels 8c..8c+7) of voxel
// wave*8+v via 16 scalar loads (6 x 32B segments per instr) and stores one
// uint4 -> wave store = 768 B contiguous. ~30 VGPR, no big arrays.
// ---------------------------------------------------------------------------
__global__ __launch_bounds__(256) void fuse_transpose_kernel(
    const float* __restrict__ k0, const float* __restrict__ former,
    ushort_t* __restrict__ grid_t)
{
    const int t    = blockIdx.x * 256 + threadIdx.x;
    const int wave = t >> 6;
    const int lane = t & 63;
    if (lane >= 48) return;
    const int c   = lane >> 3;        // chunk 0..5
    const int v   = lane & 7;
    const int vox = wave * 8 + v;

    float s[8];
#pragma unroll
    for (int k = 0; k < 8; ++k) {
        const size_t off = (size_t)(8*c + k) * NVOX + vox;
        s[k] = k0[off] + former[off];
    }
    uint4 u;
    u.x = (uint)f2bf_rne(s[0]) | ((uint)f2bf_rne(s[1]) << 16);
    u.y = (uint)f2bf_rne(s[2]) | ((uint)f2bf_rne(s[3]) << 16);
    u.z = (uint)f2bf_rne(s[4]) | ((uint)f2bf_rne(s[5]) << 16);
    u.w = (uint)f2bf_rne(s[6]) | ((uint)f2bf_rne(s[7]) << 16);
    reinterpret_cast<uint4*>(grid_t)[(size_t)vox * 6 + c] = u;
}

// ---------------------------------------------------------------------------
// Binning passes
// ---------------------------------------------------------------------------
__global__ __launch_bounds__(256) void count_kernel(
    const float* __restrict__ pts, uint* __restrict__ count)
{
    const int n = blockIdx.x * 256 + threadIdx.x;
    if (n >= NPTS) return;
    const PtGeo g = pt_geo(pts, n);
    atomicAdd(&count[pt_bin(g)], 1u);
}

// single block of 1024 threads: exclusive scan of 4096 counts -> cursor
__global__ __launch_bounds__(1024) void scan_kernel(
    const uint* __restrict__ count, uint* __restrict__ cursor)
{
    __shared__ uint part[1024];
    const int t = threadIdx.x;
    const uint c0 = count[t*4+0], c1 = count[t*4+1], c2 = count[t*4+2], c3 = count[t*4+3];
    const uint s  = c0 + c1 + c2 + c3;
    part[t] = s;
    __syncthreads();
    for (int off = 1; off < 1024; off <<= 1) {
        uint v = (t >= off) ? part[t-off] : 0u;
        __syncthreads();
        part[t] += v;
        __syncthreads();
    }
    const uint ex = part[t] - s;          // exclusive prefix of this group of 4
    cursor[t*4+0] = ex;
    cursor[t*4+1] = ex + c0;
    cursor[t*4+2] = ex + c0 + c1;
    cursor[t*4+3] = ex + c0 + c1 + c2;
}

__global__ __launch_bounds__(256) void scatter_kernel(
    const float* __restrict__ pts, uint* __restrict__ cursor, uint* __restrict__ order)
{
    const int n = blockIdx.x * 256 + threadIdx.x;
    if (n >= NPTS) return;
    const PtGeo g = pt_geo(pts, n);
    const uint pos = atomicAdd(&cursor[pt_bin(g)], 1u);
    order[pos] = (uint)n;
}

// ---------------------------------------------------------------------------
// Kernel 2 v4 (binned): 2 lanes/point over bin-sorted order; XCD-chunked
// block swizzle keeps consecutive sorted chunks on one XCD -> bin bricks
// (~68 KB) stay L2-resident. Plain stores (R4: nontemporal amplified
// WRITE_SIZE 400->656 MB).
// ---------------------------------------------------------------------------
__global__ __launch_bounds__(256) void sample_binned(
    const float* __restrict__ pts, const ushort_t* __restrict__ grid_t,
    const uint* __restrict__ order, float* __restrict__ out)
{
    // 16384 blocks; XCD chunking: block b -> sorted chunk (b%8)*2048 + b/8
    const int swz = (blockIdx.x & 7) * 2048 + (blockIdx.x >> 3);
    const int i   = swz * 128 + (threadIdx.x >> 1);
    const int sub = threadIdx.x & 1;
    const int n   = (int)order[i];

    const PtGeo g = pt_geo(pts, n);
    const float wx0 = 1.0f - g.wx, wy0 = 1.0f - g.wy, wz0 = 1.0f - g.wz;

    const int HWn = HH*WW;
    const int bz0 = g.z0*HWn, bz1 = g.z1*HWn;
    const int by0 = g.y0*WW,  by1 = g.y1*WW;

    const int vox[8] = { bz0+by0+g.x0, bz0+by0+g.x1, bz0+by1+g.x0, bz0+by1+g.x1,
                         bz1+by0+g.x0, bz1+by0+g.x1, bz1+by1+g.x0, bz1+by1+g.x1 };
    const float w[8] = { wx0*wy0*wz0, g.wx*wy0*wz0, wx0*g.wy*wz0, g.wx*g.wy*wz0,
                         wx0*wy0*g.wz, g.wx*wy0*g.wz, wx0*g.wy*g.wz, g.wx*g.wy*g.wz };

    uint4 L[8][3];
#pragma unroll
    for (int c = 0; c < 8; ++c) {
        const uint4* p = reinterpret_cast<const uint4*>(grid_t + (size_t)vox[c] * CCH);
#pragma unroll
        for (int j = 0; j < 3; ++j) L[c][j] = p[2*j + sub];
    }

    float acc[3][8];
#pragma unroll
    for (int j = 0; j < 3; ++j)
#pragma unroll
        for (int q = 0; q < 8; ++q) acc[j][q] = 0.0f;

#pragma unroll
    for (int c = 0; c < 8; ++c) {
        const float wc = w[c];
#pragma unroll
        for (int j = 0; j < 3; ++j) {
            const uint* us = reinterpret_cast<const uint*>(&L[c][j]);
#pragma unroll
            for (int q = 0; q < 4; ++q) {
                acc[j][2*q]   = fmaf(wc, __uint_as_float(us[q] << 16),         acc[j][2*q]);
                acc[j][2*q+1] = fmaf(wc, __uint_as_float(us[q] & 0xffff0000u), acc[j][2*q+1]);
            }
        }
    }

    float4* o = reinterpret_cast<float4*>(out + (size_t)n * CCH);
#pragma unroll
    for (int j = 0; j < 3; ++j) {
        const int gidx = 2*j + sub;
        o[2*gidx+0] = make_float4(acc[j][0], acc[j][1], acc[j][2], acc[j][3]);
        o[2*gidx+1] = make_float4(acc[j][4], acc[j][5], acc[j][6], acc[j][7]);
    }
}

// Flat variant (no binning) — fallback if ws fits only grid_t.
__global__ __launch_bounds__(256) void sample_flat(
    const float* __restrict__ pts, const ushort_t* __restrict__ grid_t,
    float* __restrict__ out)
{
    const int tid = blockIdx.x * 256 + threadIdx.x;
    const int n   = tid >> 1;
    const int sub = tid & 1;

    const PtGeo g = pt_geo(pts, n);
    const float wx0 = 1.0f - g.wx, wy0 = 1.0f - g.wy, wz0 = 1.0f - g.wz;
    const int HWn = HH*WW;
    const int bz0 = g.z0*HWn, bz1 = g.z1*HWn;
    const int by0 = g.y0*WW,  by1 = g.y1*WW;
    const int vox[8] = { bz0+by0+g.x0, bz0+by0+g.x1, bz0+by1+g.x0, bz0+by1+g.x1,
                         bz1+by0+g.x0, bz1+by0+g.x1, bz1+by1+g.x0, bz1+by1+g.x1 };
    const float w[8] = { wx0*wy0*wz0, g.wx*wy0*wz0, wx0*g.wy*wz0, g.wx*g.wy*wz0,
                         wx0*wy0*g.wz, g.wx*wy0*g.wz, wx0*g.wy*g.wz, g.wx*g.wy*g.wz };

    uint4 L[8][3];
#pragma unroll
    for (int c = 0; c < 8; ++c) {
        const uint4* p = reinterpret_cast<const uint4*>(grid_t + (size_t)vox[c] * CCH);
#pragma unroll
        for (int j = 0; j < 3; ++j) L[c][j] = p[2*j + sub];
    }
    float acc[3][8];
#pragma unroll
    for (int j = 0; j < 3; ++j)
#pragma unroll
        for (int q = 0; q < 8; ++q) acc[j][q] = 0.0f;
#pragma unroll
    for (int c = 0; c < 8; ++c) {
        const float wc = w[c];
#pragma unroll
        for (int j = 0; j < 3; ++j) {
            const uint* us = reinterpret_cast<const uint*>(&L[c][j]);
#pragma unroll
            for (int q = 0; q < 4; ++q) {
                acc[j][2*q]   = fmaf(wc, __uint_as_float(us[q] << 16),         acc[j][2*q]);
                acc[j][2*q+1] = fmaf(wc, __uint_as_float(us[q] & 0xffff0000u), acc[j][2*q+1]);
            }
        }
    }
    float4* o = reinterpret_cast<float4*>(out + (size_t)n * CCH);
#pragma unroll
    for (int j = 0; j < 3; ++j) {
        const int gidx = 2*j + sub;
        o[2*gidx+0] = make_float4(acc[j][0], acc[j][1], acc[j][2], acc[j][3]);
        o[2*gidx+1] = make_float4(acc[j][4], acc[j][5], acc[j][6], acc[j][7]);
    }
}

// Last-resort fallback: direct f32 gather.
__global__ __launch_bounds__(256) void sample_naive(
    const float* __restrict__ pts, const float* __restrict__ k0,
    const float* __restrict__ former, float* __restrict__ out)
{
    const int n = blockIdx.x * 256 + threadIdx.x;
    if (n >= NPTS) return;
    const PtGeo g = pt_geo(pts, n);
    const float wx0 = 1.0f - g.wx, wy0 = 1.0f - g.wy, wz0 = 1.0f - g.wz;
    const int HWn = HH*WW;
    const int v000 = g.z0*HWn + g.y0*WW + g.x0, v100 = g.z0*HWn + g.y0*WW + g.x1;
    const int v010 = g.z0*HWn + g.y1*WW + g.x0, v110 = g.z0*HWn + g.y1*WW + g.x1;
    const int v001 = g.z1*HWn + g.y0*WW + g.x0, v101 = g.z1*HWn + g.y0*WW + g.x1;
    const int v011 = g.z1*HWn + g.y1*WW + g.x0, v111 = g.z1*HWn + g.y1*WW + g.x1;
    const float w000 = wx0*wy0*wz0, w100 = g.wx*wy0*wz0;
    const float w010 = wx0*g.wy*wz0, w110 = g.wx*g.wy*wz0;
    const float w001 = wx0*wy0*g.wz, w101 = g.wx*wy0*g.wz;
    const float w011 = wx0*g.wy*g.wz, w111 = g.wx*g.wy*g.wz;
    for (int c = 0; c < CCH; ++c) {
        const float* g0 = k0     + (size_t)c * NVOX;
        const float* g1 = former + (size_t)c * NVOX;
        float s = 0.0f;
        s += w000 * (g0[v000] + g1[v000]);
        s += w100 * (g0[v100] + g1[v100]);
        s += w010 * (g0[v010] + g1[v010]);
        s += w110 * (g0[v110] + g1[v110]);
        s += w001 * (g0[v001] + g1[v001]);
        s += w101 * (g0[v101] + g1[v101]);
        s += w011 * (g0[v011] + g1[v011]);
        s += w111 * (g0[v111] + g1[v111]);
        out[(size_t)n*CCH + c] = s;
    }
}

extern "C" void kernel_launch(void* const* d_in, const int* in_sizes, int n_in,
                              void* d_out, int out_size, void* d_ws, size_t ws_size,
                              hipStream_t stream) {
    const float* ray_pts = (const float*)d_in[0];
    const float* k0      = (const float*)d_in[1];
    const float* former  = (const float*)d_in[2];
    float* out = (float*)d_out;

    const size_t grid_bytes  = (size_t)NVOX * CCH * sizeof(ushort_t); // 201,326,592
    const size_t order_bytes = (size_t)NPTS * sizeof(uint);           //   8,388,608
    const size_t bins_bytes  = (size_t)NBINS * sizeof(uint);          //      16,384
    const size_t need_binned = grid_bytes + order_bytes + 2*bins_bytes;

    if (ws_size >= grid_bytes) {
        ushort_t* grid_t = (ushort_t*)d_ws;
        fuse_transpose_kernel<<<NVOX/32, 256, 0, stream>>>(k0, former, grid_t);
        if (ws_size >= need_binned) {
            uint* order  = (uint*)((char*)d_ws + grid_bytes);
            uint* count  = order + NPTS;
            uint* cursor = count + NBINS;
            hipMemsetAsync(count, 0, bins_bytes, stream);
            count_kernel  <<<NPTS/256, 256, 0, stream>>>(ray_pts, count);
            scan_kernel   <<<1, 1024, 0, stream>>>(count, cursor);
            scatter_kernel<<<NPTS/256, 256, 0, stream>>>(ray_pts, cursor, order);
            sample_binned <<<NPTS/128, 256, 0, stream>>>(ray_pts, grid_t, order, out);
        } else {
            sample_flat<<<(NPTS*2)/256, 256, 0, stream>>>(ray_pts, grid_t, out);
        }
    } else {
        sample_naive<<<NPTS/256, 256, 0, stream>>>(ray_pts, k0, former, out);
    }
}

// Round 6
// 659.643 us; speedup vs baseline: 1.3723x; 1.3723x over previous
//
#include <hip/hip_runtime.h>
#include <hip/hip_bf16.h>
#include <cstdint>

#define CCH 48
#define DD 128
#define HH 128
#define WW 128
#define NVOX (DD*HH*WW)        // 2,097,152 voxels
#define NPTS 2097152
// Bricks: 8x8x4 voxels (x,y,z); halo 9x9x5 = 405 voxels
#define NBINS 8192             // 16 x 16 x 32 (bx, by, bz)
#define BRICK_VOX 405

typedef unsigned int uint;
typedef unsigned short ushort_t;

__device__ __forceinline__ ushort_t f2bf_rne(float f) {
    uint u = __float_as_uint(f);
    uint r = (u + 0x7fffu + ((u >> 16) & 1u)) >> 16;
    return (ushort_t)r;
}

struct PtGeo {
    int x0, y0, z0, x1, y1, z1;
    float wx, wy, wz;
};
__device__ __forceinline__ PtGeo pt_geo(const float* __restrict__ pts, int n) {
    PtGeo g;
    const float ix = (pts[n*3+0] + 1.0f) * 63.5f;
    const float iy = (pts[n*3+1] + 1.0f) * 63.5f;
    const float iz = (pts[n*3+2] + 1.0f) * 63.5f;
    const float xf = floorf(ix), yf = floorf(iy), zf = floorf(iz);
    g.wx = ix - xf; g.wy = iy - yf; g.wz = iz - zf;
    int x0 = (int)xf, y0 = (int)yf, z0 = (int)zf;
    g.x0 = min(max(x0,0), WW-1); g.x1 = min(max(x0+1,0), WW-1);
    g.y0 = min(max(y0,0), HH-1); g.y1 = min(max(y0+1,0), HH-1);
    g.z0 = min(max(z0,0), DD-1); g.z1 = min(max(z0+1,0), DD-1);
    return g;
}
// bin = (bz<<8)|(by<<4)|bx with brick 8x8x4
__device__ __forceinline__ int pt_bin(const PtGeo& g) {
    return ((g.z0 >> 2) << 8) | ((g.y0 >> 3) << 4) | (g.x0 >> 3);
}

// ---------------------------------------------------------------------------
// Kernel 1 (reverted to R1 structure — best measured 231us): 1 voxel/thread,
// 48x2 coalesced channel-major scalar reads (256B/wave/instr), NT loads
// (streaming, read-once), 96B contiguous bf16 store.
// ---------------------------------------------------------------------------
__global__ __launch_bounds__(256) void fuse_transpose_kernel(
    const float* __restrict__ k0, const float* __restrict__ former,
    ushort_t* __restrict__ grid_t)
{
    const int v = blockIdx.x * 256 + threadIdx.x;
    float vals[CCH];
#pragma unroll
    for (int c = 0; c < CCH; ++c) {
        const size_t off = (size_t)c * NVOX + v;
        vals[c] = __builtin_nontemporal_load(k0 + off)
                + __builtin_nontemporal_load(former + off);
    }
    uint4* dst = reinterpret_cast<uint4*>(grid_t + (size_t)v * CCH);
#pragma unroll
    for (int i = 0; i < 6; ++i) {
        uint4 u;
        u.x = (uint)f2bf_rne(vals[i*8+0]) | ((uint)f2bf_rne(vals[i*8+1]) << 16);
        u.y = (uint)f2bf_rne(vals[i*8+2]) | ((uint)f2bf_rne(vals[i*8+3]) << 16);
        u.z = (uint)f2bf_rne(vals[i*8+4]) | ((uint)f2bf_rne(vals[i*8+5]) << 16);
        u.w = (uint)f2bf_rne(vals[i*8+6]) | ((uint)f2bf_rne(vals[i*8+7]) << 16);
        dst[i] = u;
    }
}

// ---------------------------------------------------------------------------
// Binning passes (structure proven in R5)
// ---------------------------------------------------------------------------
__global__ __launch_bounds__(256) void count_kernel(
    const float* __restrict__ pts, uint* __restrict__ count)
{
    const int n = blockIdx.x * 256 + threadIdx.x;
    if (n >= NPTS) return;
    const PtGeo g = pt_geo(pts, n);
    atomicAdd(&count[pt_bin(g)], 1u);
}

// 1 block x 1024 threads: exclusive scan of 8192 counts (8 per thread)
__global__ __launch_bounds__(1024) void scan_kernel(
    const uint* __restrict__ count, uint* __restrict__ cursor)
{
    __shared__ uint part[1024];
    const int t = threadIdx.x;
    uint c[8]; uint s = 0u;
#pragma unroll
    for (int k = 0; k < 8; ++k) { c[k] = count[t*8+k]; s += c[k]; }
    part[t] = s;
    __syncthreads();
    for (int off = 1; off < 1024; off <<= 1) {
        uint v = (t >= off) ? part[t-off] : 0u;
        __syncthreads();
        part[t] += v;
        __syncthreads();
    }
    uint ex = part[t] - s;
#pragma unroll
    for (int k = 0; k < 8; ++k) { cursor[t*8+k] = ex; ex += c[k]; }
}

__global__ __launch_bounds__(256) void scatter_kernel(
    const float* __restrict__ pts, uint* __restrict__ cursor, uint* __restrict__ order)
{
    const int n = blockIdx.x * 256 + threadIdx.x;
    if (n >= NPTS) return;
    const PtGeo g = pt_geo(pts, n);
    const uint pos = atomicAdd(&cursor[pt_bin(g)], 1u);
    order[pos] = (uint)n;
}

// ---------------------------------------------------------------------------
// Kernel 2 v5: one block per bin. Stage halo brick (405 vox x 96B = 38,880 B)
// into LDS with coalesced uint4 loads, then all 24 gathers/lane hit LDS.
// After scatter, cursor[b] == end; start = end - count.
// ---------------------------------------------------------------------------
__global__ __launch_bounds__(256) void sample_lds(
    const float* __restrict__ pts, const ushort_t* __restrict__ grid_t,
    const uint* __restrict__ order, const uint* __restrict__ bin_count,
    const uint* __restrict__ bin_end, float* __restrict__ out)
{
    __shared__ __align__(16) ushort_t brick[BRICK_VOX * CCH];   // 38,880 B

    // XCD-chunked swizzle: consecutive bins (x-adjacent bricks, shared halo
    // planes) stay on one XCD's L2. 8192 = 8 * 1024, bijective.
    const int b  = (blockIdx.x & 7) * 1024 + (blockIdx.x >> 3);
    const int bx = b & 15, by = (b >> 4) & 15, bz = b >> 8;

    const uint cnt   = bin_count[b];
    const uint end   = bin_end[b];
    const uint start = end - cnt;

    // ---- stage: 405 voxels * 6 uint4 = 2430 uint4, coalesced ----
    const int t = threadIdx.x;
    uint4* bl = reinterpret_cast<uint4*>(brick);
    const uint4* gsrc = reinterpret_cast<const uint4*>(grid_t);
#pragma unroll
    for (int it = 0; it < 10; ++it) {
        const int i = it * 256 + t;
        if (i < BRICK_VOX * 6) {
            const int v = i / 6, p = i % 6;
            const int lz = v / 81, rem = v % 81, ly = rem / 9, lx = rem % 9;
            const int gz = min(bz*4 + lz, DD-1);
            const int gy = min(by*8 + ly, HH-1);
            const int gx = min(bx*8 + lx, WW-1);
            bl[v*6 + p] = gsrc[(size_t)((gz*HH + gy)*WW + gx) * 6 + p];
        }
    }
    __syncthreads();
    if (cnt == 0) return;

    const int sub = t & 1;
    for (uint base = 0; base < cnt; base += 128) {
        const uint ii = base + (uint)(t >> 1);
        if (ii >= cnt) break;                   // no barriers below: safe
        const int n = (int)order[start + ii];

        const PtGeo g = pt_geo(pts, n);
        const float wx0 = 1.0f - g.wx, wy0 = 1.0f - g.wy, wz0 = 1.0f - g.wz;

        // local brick coords (x1/z1 clamping matches halo clamping)
        const int lx0 = g.x0 - bx*8, lx1 = g.x1 - bx*8;
        const int ly0 = g.y0 - by*8, ly1 = g.y1 - by*8;
        const int lz0 = g.z0 - bz*4, lz1 = g.z1 - bz*4;

        const int r0 = lz0*81, r1 = lz1*81;
        const int s0 = ly0*9,  s1 = ly1*9;
        const int vox[8] = { r0+s0+lx0, r0+s0+lx1, r0+s1+lx0, r0+s1+lx1,
                             r1+s0+lx0, r1+s0+lx1, r1+s1+lx0, r1+s1+lx1 };
        const float w[8] = { wx0*wy0*wz0,  g.wx*wy0*wz0,  wx0*g.wy*wz0,  g.wx*g.wy*wz0,
                             wx0*wy0*g.wz, g.wx*wy0*g.wz, wx0*g.wy*g.wz, g.wx*g.wy*g.wz };

        float acc[3][8];
#pragma unroll
        for (int j = 0; j < 3; ++j)
#pragma unroll
            for (int q = 0; q < 8; ++q) acc[j][q] = 0.0f;

        // two batches of 4 corners: 12 LDS b128 reads in flight each
#pragma unroll
        for (int half = 0; half < 2; ++half) {
            uint4 L[4][3];
#pragma unroll
            for (int c = 0; c < 4; ++c) {
#pragma unroll
                for (int j = 0; j < 3; ++j)
                    L[c][j] = bl[vox[half*4 + c]*6 + 2*j + sub];
            }
#pragma unroll
            for (int c = 0; c < 4; ++c) {
                const float wc = w[half*4 + c];
#pragma unroll
                for (int j = 0; j < 3; ++j) {
                    const uint* us = reinterpret_cast<const uint*>(&L[c][j]);
#pragma unroll
                    for (int q = 0; q < 4; ++q) {
                        acc[j][2*q]   = fmaf(wc, __uint_as_float(us[q] << 16),         acc[j][2*q]);
                        acc[j][2*q+1] = fmaf(wc, __uint_as_float(us[q] & 0xffff0000u), acc[j][2*q+1]);
                    }
                }
            }
        }

        float4* o = reinterpret_cast<float4*>(out + (size_t)n * CCH);
#pragma unroll
        for (int j = 0; j < 3; ++j) {
            const int gidx = 2*j + sub;
            o[2*gidx+0] = make_float4(acc[j][0], acc[j][1], acc[j][2], acc[j][3]);
            o[2*gidx+1] = make_float4(acc[j][4], acc[j][5], acc[j][6], acc[j][7]);
        }
    }
}

// Flat fallback (ws fits only grid_t) — R4 structure minus NT stores.
__global__ __launch_bounds__(256) void sample_flat(
    const float* __restrict__ pts, const ushort_t* __restrict__ grid_t,
    float* __restrict__ out)
{
    const int tid = blockIdx.x * 256 + threadIdx.x;
    const int n   = tid >> 1;
    const int sub = tid & 1;

    const PtGeo g = pt_geo(pts, n);
    const float wx0 = 1.0f - g.wx, wy0 = 1.0f - g.wy, wz0 = 1.0f - g.wz;
    const int HWn = HH*WW;
    const int bz0 = g.z0*HWn, bz1 = g.z1*HWn;
    const int by0 = g.y0*WW,  by1 = g.y1*WW;
    const int vox[8] = { bz0+by0+g.x0, bz0+by0+g.x1, bz0+by1+g.x0, bz0+by1+g.x1,
                         bz1+by0+g.x0, bz1+by0+g.x1, bz1+by1+g.x0, bz1+by1+g.x1 };
    const float w[8] = { wx0*wy0*wz0,  g.wx*wy0*wz0,  wx0*g.wy*wz0,  g.wx*g.wy*wz0,
                         wx0*wy0*g.wz, g.wx*wy0*g.wz, wx0*g.wy*g.wz, g.wx*g.wy*g.wz };

    uint4 L[8][3];
#pragma unroll
    for (int c = 0; c < 8; ++c) {
        const uint4* p = reinterpret_cast<const uint4*>(grid_t + (size_t)vox[c] * CCH);
#pragma unroll
        for (int j = 0; j < 3; ++j) L[c][j] = p[2*j + sub];
    }
    float acc[3][8];
#pragma unroll
    for (int j = 0; j < 3; ++j)
#pragma unroll
        for (int q = 0; q < 8; ++q) acc[j][q] = 0.0f;
#pragma unroll
    for (int c = 0; c < 8; ++c) {
        const float wc = w[c];
#pragma unroll
        for (int j = 0; j < 3; ++j) {
            const uint* us = reinterpret_cast<const uint*>(&L[c][j]);
#pragma unroll
            for (int q = 0; q < 4; ++q) {
                acc[j][2*q]   = fmaf(wc, __uint_as_float(us[q] << 16),         acc[j][2*q]);
                acc[j][2*q+1] = fmaf(wc, __uint_as_float(us[q] & 0xffff0000u), acc[j][2*q+1]);
            }
        }
    }
    float4* o = reinterpret_cast<float4*>(out + (size_t)n * CCH);
#pragma unroll
    for (int j = 0; j < 3; ++j) {
        const int gidx = 2*j + sub;
        o[2*gidx+0] = make_float4(acc[j][0], acc[j][1], acc[j][2], acc[j][3]);
        o[2*gidx+1] = make_float4(acc[j][4], acc[j][5], acc[j][6], acc[j][7]);
    }
}

// Last-resort fallback: direct f32 gather.
__global__ __launch_bounds__(256) void sample_naive(
    const float* __restrict__ pts, const float* __restrict__ k0,
    const float* __restrict__ former, float* __restrict__ out)
{
    const int n = blockIdx.x * 256 + threadIdx.x;
    if (n >= NPTS) return;
    const PtGeo g = pt_geo(pts, n);
    const float wx0 = 1.0f - g.wx, wy0 = 1.0f - g.wy, wz0 = 1.0f - g.wz;
    const int HWn = HH*WW;
    const int v000 = g.z0*HWn + g.y0*WW + g.x0, v100 = g.z0*HWn + g.y0*WW + g.x1;
    const int v010 = g.z0*HWn + g.y1*WW + g.x0, v110 = g.z0*HWn + g.y1*WW + g.x1;
    const int v001 = g.z1*HWn + g.y0*WW + g.x0, v101 = g.z1*HWn + g.y0*WW + g.x1;
    const int v011 = g.z1*HWn + g.y1*WW + g.x0, v111 = g.z1*HWn + g.y1*WW + g.x1;
    const float w000 = wx0*wy0*wz0,  w100 = g.wx*wy0*wz0;
    const float w010 = wx0*g.wy*wz0, w110 = g.wx*g.wy*wz0;
    const float w001 = wx0*wy0*g.wz, w101 = g.wx*wy0*g.wz;
    const float w011 = wx0*g.wy*g.wz, w111 = g.wx*g.wy*g.wz;
    for (int c = 0; c < CCH; ++c) {
        const float* g0 = k0     + (size_t)c * NVOX;
        const float* g1 = former + (size_t)c * NVOX;
        float s = 0.0f;
        s += w000 * (g0[v000] + g1[v000]);
        s += w100 * (g0[v100] + g1[v100]);
        s += w010 * (g0[v010] + g1[v010]);
        s += w110 * (g0[v110] + g1[v110]);
        s += w001 * (g0[v001] + g1[v001]);
        s += w101 * (g0[v101] + g1[v101]);
        s += w011 * (g0[v011] + g1[v011]);
        s += w111 * (g0[v111] + g1[v111]);
        out[(size_t)n*CCH + c] = s;
    }
}

extern "C" void kernel_launch(void* const* d_in, const int* in_sizes, int n_in,
                              void* d_out, int out_size, void* d_ws, size_t ws_size,
                              hipStream_t stream) {
    const float* ray_pts = (const float*)d_in[0];
    const float* k0      = (const float*)d_in[1];
    const float* former  = (const float*)d_in[2];
    float* out = (float*)d_out;

    const size_t grid_bytes  = (size_t)NVOX * CCH * sizeof(ushort_t); // 201,326,592
    const size_t order_bytes = (size_t)NPTS * sizeof(uint);           //   8,388,608
    const size_t bins_bytes  = (size_t)NBINS * sizeof(uint);          //      32,768
    const size_t need_binned = grid_bytes + order_bytes + 2*bins_bytes;

    if (ws_size >= grid_bytes) {
        ushort_t* grid_t = (ushort_t*)d_ws;
        fuse_transpose_kernel<<<NVOX/256, 256, 0, stream>>>(k0, former, grid_t);
        if (ws_size >= need_binned) {
            uint* order  = (uint*)((char*)d_ws + grid_bytes);
            uint* count  = order + NPTS;
            uint* cursor = count + NBINS;
            hipMemsetAsync(count, 0, bins_bytes, stream);
            count_kernel  <<<NPTS/256, 256, 0, stream>>>(ray_pts, count);
            scan_kernel   <<<1, 1024, 0, stream>>>(count, cursor);
            scatter_kernel<<<NPTS/256, 256, 0, stream>>>(ray_pts, cursor, order);
            sample_lds    <<<NBINS, 256, 0, stream>>>(ray_pts, grid_t, order, count, cursor, out);
        } else {
            sample_flat<<<(NPTS*2)/256, 256, 0, stream>>>(ray_pts, grid_t, out);
        }
    } else {
        sample_naive<<<NPTS/256, 256, 0, stream>>>(ray_pts, k0, former, out);
    }
}